// Round 8
// baseline (848.508 us; speedup 1.0000x reference)
//
#include <hip/hip_runtime.h>
#include <stdint.h>

#define AS1 __attribute__((address_space(1)))
#define AS3 __attribute__((address_space(3)))

typedef __bf16 bf16x8 __attribute__((ext_vector_type(8)));
typedef float f32x4 __attribute__((ext_vector_type(4)));

static __device__ __forceinline__ float bf2f(unsigned short u) {
    union { unsigned int i; float f; } x; x.i = ((unsigned int)u) << 16; return x.f;
}
static __device__ __forceinline__ unsigned short f2bf(float f) {
    union { float f; unsigned int i; } x; x.f = f;
    unsigned int u = x.i;
    unsigned int r = (u + 0x7fffu + ((u >> 16) & 1u)) >> 16;  // RNE
    return (unsigned short)r;
}

static __device__ __forceinline__ void gll16(const void* g, void* l) {
    __builtin_amdgcn_global_load_lds((const AS1 unsigned int*)g,
                                     (AS3 unsigned int*)l, 16, 0, 0);
}

// ---------------- fused preprocessing ----------------
// block-range dispatch (branch is block-uniform -> barriers legal):
//   [0,4096)          : hs fp32 -> bf16 (vec4)
//   [4096,10240)      : w_qkvz [2048,12288] -> wqT [12288,2048] bf16 (64x64 tiles)
//   [10240,12288)     : w_out  [4096,2048]  -> woT [2048,4096]  bf16
//   [12288,12544)     : ba GEMM + beta/g
#define NB_CVT 4096
#define NB_TQ  6144
#define NB_TO  2048
#define NB_BAG 256

static __device__ __forceinline__ void transpose64(
    const float* __restrict__ src, unsigned short* __restrict__ dst,
    int R, int C, int bx, int by, float (*tile)[66], int tid) {
    int r0 = by * 64, c0 = bx * 64;
    int q = tid >> 6, l = tid & 63;
    int lr = l >> 4, lc4 = (l & 15) * 4;
#pragma unroll
    for (int i = 0; i < 4; i++) {
        int row = q * 16 + i * 4 + lr;
        float4 v = *(const float4*)(src + (size_t)(r0 + row) * C + c0 + lc4);
        tile[row][lc4] = v.x; tile[row][lc4 + 1] = v.y;
        tile[row][lc4 + 2] = v.z; tile[row][lc4 + 3] = v.w;
    }
    __syncthreads();
#pragma unroll
    for (int j = 0; j < 2; j++) {
        int col = j * 32 + (tid >> 3);
        int rr = (tid & 7) * 8;
        unsigned short tmp[8];
#pragma unroll
        for (int e = 0; e < 8; e++) tmp[e] = f2bf(tile[rr + e][col]);
        *(uint4*)(dst + (size_t)(c0 + col) * R + r0 + rr) = *(const uint4*)tmp;
    }
}

__global__ __launch_bounds__(256) void preproc_kernel(
    const float* __restrict__ hs, unsigned short* __restrict__ hsb,
    const float* __restrict__ w_qkvz, unsigned short* __restrict__ wqT,
    const float* __restrict__ w_out, unsigned short* __restrict__ woT,
    const float* __restrict__ w_ba, const float* __restrict__ A_log,
    const float* __restrict__ dt_bias,
    float* __restrict__ gg, float* __restrict__ bb) {
    __shared__ float tile[64][66];
    int bid = blockIdx.x;
    int tid = threadIdx.x;
    if (bid < NB_CVT) {
        int i = bid * 256 + tid;
        float4 v = ((const float4*)hs)[i];
        ushort4 o;
        o.x = f2bf(v.x); o.y = f2bf(v.y); o.z = f2bf(v.z); o.w = f2bf(v.w);
        ((ushort4*)hsb)[i] = o;
    } else if (bid < NB_CVT + NB_TQ) {
        int b2 = bid - NB_CVT;
        transpose64(w_qkvz, wqT, 2048, 12288, b2 >> 5, b2 & 31, tile, tid);
    } else if (bid < NB_CVT + NB_TQ + NB_TO) {
        int b3 = bid - (NB_CVT + NB_TQ);
        transpose64(w_out, woT, 4096, 2048, b3 & 31, b3 >> 5, tile, tid);
    } else {
        int b4 = bid - (NB_CVT + NB_TQ + NB_TO);
        int w = tid >> 6, lane = tid & 63;
        int r0 = b4 * 8 + w * 2;
        const float* h0 = hs + (size_t)r0 * 2048;
        float a0 = 0.f, a1 = 0.f;
#pragma unroll 4
        for (int k = 0; k < 2048; k++) {
            float wv = w_ba[k * 64 + lane];
            a0 += h0[k] * wv;
            a1 += h0[2048 + k] * wv;
        }
        int h = lane >> 2, idx = lane & 3;
        int vh = h * 2 + (idx & 1);
        float accs[2] = {a0, a1};
#pragma unroll
        for (int j = 0; j < 2; j++) {
            int t = r0 + j;
            float acc = accs[j];
            if (idx < 2) {
                bb[t * 32 + vh] = 1.f / (1.f + expf(-acc));
            } else {
                float x = acc + dt_bias[vh];
                float sp = fmaxf(x, 0.f) + log1pf(expf(-fabsf(x)));
                gg[t * 32 + vh] = -expf(A_log[vh]) * sp;
            }
        }
    }
}

// ---------------- bf16 MFMA GEMM: C = A[M,K] * Bt[N,K]^T ----------------
// blockIdx.z = K-slice (split-K): fp32 partials to C + z*M*N.
template <int STORE_BF16>
__global__ __launch_bounds__(256) void gemm_bt_kernel(
    const unsigned short* __restrict__ A, const unsigned short* __restrict__ Bt,
    void* __restrict__ C, int M, int N, int K) {
    __shared__ __align__(16) unsigned short As[128 * 32];
    __shared__ __align__(16) unsigned short Bs[128 * 32];
    int tid = threadIdx.x;
    int lane = tid & 63;
    int w = tid >> 6;
    int m0 = blockIdx.y * 128;
    int n0 = blockIdx.x * 128;
    int zz = blockIdx.z;
    int Kz = K / gridDim.z;
    int qd = lane >> 4, rc = lane & 15;
    int wm = (w >> 1) * 64, wn = (w & 1) * 64;

    f32x4 acc[4][4];
#pragma unroll
    for (int i = 0; i < 4; i++)
#pragma unroll
        for (int j = 0; j < 4; j++)
#pragma unroll
            for (int r = 0; r < 4; r++) acc[i][j][r] = 0.f;

    int s0 = w * 128 + lane;
    int s1 = s0 + 64;
    int rA0 = s0 >> 2, cs0 = (s0 & 3) * 8;
    int rA1 = s1 >> 2, cs1 = (s1 & 3) * 8;
    const unsigned short* a0 = A + (size_t)(m0 + rA0) * K + cs0 + (size_t)zz * Kz;
    const unsigned short* a1 = A + (size_t)(m0 + rA1) * K + cs1 + (size_t)zz * Kz;
    const unsigned short* b0 = Bt + (size_t)(n0 + rA0) * K + cs0 + (size_t)zz * Kz;
    const unsigned short* b1 = Bt + (size_t)(n0 + rA1) * K + cs1 + (size_t)zz * Kz;
    unsigned short* lA0 = As + s0 * 8;
    unsigned short* lA1 = As + s1 * 8;
    unsigned short* lB0 = Bs + s0 * 8;
    unsigned short* lB1 = Bs + s1 * 8;

    for (int k0 = 0; k0 < Kz; k0 += 32) {
        __syncthreads();
        gll16(a0 + k0, lA0);
        gll16(a1 + k0, lA1);
        gll16(b0 + k0, lB0);
        gll16(b1 + k0, lB1);
        __syncthreads();
        bf16x8 af[4], bfr[4];
#pragma unroll
        for (int i = 0; i < 4; i++)
            af[i] = *(const bf16x8*)(As + (wm + i * 16 + rc) * 32 + qd * 8);
#pragma unroll
        for (int i = 0; i < 4; i++)
            bfr[i] = *(const bf16x8*)(Bs + (wn + i * 16 + rc) * 32 + qd * 8);
#pragma unroll
        for (int i = 0; i < 4; i++)
#pragma unroll
            for (int j = 0; j < 4; j++)
                acc[i][j] = __builtin_amdgcn_mfma_f32_16x16x32_bf16(af[i], bfr[j], acc[i][j], 0, 0, 0);
    }

#pragma unroll
    for (int i = 0; i < 4; i++)
#pragma unroll
        for (int j = 0; j < 4; j++)
#pragma unroll
            for (int r = 0; r < 4; r++) {
                int row = m0 + wm + i * 16 + qd * 4 + r;
                int col = n0 + wn + j * 16 + rc;
                if (STORE_BF16)
                    ((unsigned short*)C)[(size_t)row * N + col] = f2bf(acc[i][j][r]);
                else
                    ((float*)C)[(size_t)zz * M * N + (size_t)row * N + col] = acc[i][j][r];
            }
}

// ---------------- split-K partial sum: out = p[0] + p[1] ----------------
__global__ __launch_bounds__(256) void add_out_kernel(
    const float* __restrict__ p, float* __restrict__ out, int n4) {
    int i = blockIdx.x * 256 + threadIdx.x;
    if (i >= n4) return;
    float4 a = ((const float4*)p)[i];
    float4 b = ((const float4*)(p + (size_t)n4 * 4))[i];
    ((float4*)out)[i] = make_float4(a.x + b.x, a.y + b.y, a.z + b.z, a.w + b.w);
}

// ---------------- depthwise causal conv(4) + silu + l2norm(q,k) ----------------
__global__ __launch_bounds__(256) void conv_kernel(
    const unsigned short* __restrict__ qkvz, const float* __restrict__ conv_w,
    unsigned short* __restrict__ qb, unsigned short* __restrict__ kb,
    float* __restrict__ vv) {
    __shared__ float xs[8192];
    __shared__ float rs[32];
    int t = blockIdx.x;
    int s = t & 1023;
    int tid = threadIdx.x;
    size_t rowbase = (size_t)t * 12288;
#pragma unroll
    for (int i = 0; i < 4; i++) {
        int c = (i * 256 + tid) * 8;
        int d = c & 127;
        int col;
        if (c < 2048) col = (c >> 7) * 768 + d;
        else if (c < 4096) col = ((c - 2048) >> 7) * 768 + 128 + d;
        else { int vh2 = (c - 4096) >> 7; col = (vh2 >> 1) * 768 + 256 + (vh2 & 1) * 128 + d; }
        float wts[8][4];
#pragma unroll
        for (int e = 0; e < 8; e++) {
            float4 t4 = *(const float4*)(conv_w + (size_t)(c + e) * 4);
            wts[e][0] = t4.x; wts[e][1] = t4.y; wts[e][2] = t4.z; wts[e][3] = t4.w;
        }
        float acc[8] = {0.f, 0.f, 0.f, 0.f, 0.f, 0.f, 0.f, 0.f};
#pragma unroll
        for (int j = 0; j < 4; j++) {
            int ss = s - 3 + j;
            if (ss >= 0) {
                uint4 u = *(const uint4*)(qkvz + rowbase + (size_t)(j - 3) * 12288 + col);
                const unsigned short* us = (const unsigned short*)&u;
#pragma unroll
                for (int e = 0; e < 8; e++) acc[e] += bf2f(us[e]) * wts[e][j];
            }
        }
#pragma unroll
        for (int e = 0; e < 8; e++) xs[c + e] = acc[e] / (1.f + expf(-acc[e]));
    }
    __syncthreads();
    {
        int seg = tid >> 3, part = tid & 7;
        const float* pp = xs + seg * 128 + part * 16;
        float s2 = 0.f;
#pragma unroll
        for (int j = 0; j < 16; j++) s2 += pp[j] * pp[j];
        s2 += __shfl_xor(s2, 1);
        s2 += __shfl_xor(s2, 2);
        s2 += __shfl_xor(s2, 4);
        if (part == 0) rs[seg] = rsqrtf(s2 + 1e-6f);
    }
    __syncthreads();
    const float QS = 0.08838834764831845f;  // 128^-0.5
#pragma unroll
    for (int i = 0; i < 4; i++) {
        int c = (i * 256 + tid) * 8;
        float x[8];
#pragma unroll
        for (int e = 0; e < 8; e++) x[e] = xs[c + e];
        if (c < 4096) {
            float sc = (c < 2048) ? rs[c >> 7] * QS : rs[((c - 2048) >> 7) + 16];
            uint4 o;
            o.x = (unsigned)f2bf(x[0] * sc) | ((unsigned)f2bf(x[1] * sc) << 16);
            o.y = (unsigned)f2bf(x[2] * sc) | ((unsigned)f2bf(x[3] * sc) << 16);
            o.z = (unsigned)f2bf(x[4] * sc) | ((unsigned)f2bf(x[5] * sc) << 16);
            o.w = (unsigned)f2bf(x[6] * sc) | ((unsigned)f2bf(x[7] * sc) << 16);
            if (c < 2048) *(uint4*)(qb + (size_t)t * 2048 + c) = o;
            else *(uint4*)(kb + (size_t)t * 2048 + c - 2048) = o;
        } else {
            float* vp = vv + (size_t)t * 4096 + c - 4096;
            *(float4*)vp = make_float4(x[0], x[1], x[2], x[3]);
            *(float4*)(vp + 4) = make_float4(x[4], x[5], x[6], x[7]);
        }
    }
}

// ---------------- delta-rule prep (parallel over 64 bh x 16 chunks) ----------------
__global__ __launch_bounds__(256, 2) void prep_kernel(
    const unsigned short* __restrict__ qb, const unsigned short* __restrict__ kb,
    const float* __restrict__ vv, const float* __restrict__ gg,
    const float* __restrict__ bb,
    unsigned short* __restrict__ Wg, unsigned short* __restrict__ DlT,
    unsigned short* __restrict__ KtT, unsigned short* __restrict__ Pt,
    float* __restrict__ lamg, float* __restrict__ l64g) {
    __shared__ __align__(16) unsigned short Tb[64 * 72];    // -beta_i E_ij A_ij (i>j)
    __shared__ __align__(16) unsigned short Xw[4][64 * 72]; // per-wave solutions [col][tok]
    __shared__ float Td[4 * 16 * 17];                       // +T diag blocks fp32
    __shared__ float RHSw[4][16 * 68];                      // per-wave stage scratch
    __shared__ float cc[64], bet[64], lam_s[64], ex64[64];

    int bid = blockIdx.x;            // bh*16 + ch
    int ch = bid & 15, bh = bid >> 4;
    int vh = bh & 31, b = bh >> 5;
    int hk = vh >> 1;
    int t0 = b * 1024 + ch * 64;
    int tid = threadIdx.x, wv = tid >> 6, lane = tid & 63;
    int qd = lane >> 4, rc = lane & 15;
    int rowb = (wv & 1) * 32;
    size_t obase = (size_t)bid * 8192;
    size_t pbase = (size_t)bid * 4096;

    if (tid < 64) {
        float x = gg[(size_t)(t0 + tid) * 32 + vh];
#pragma unroll
        for (int ofs = 1; ofs < 64; ofs <<= 1) {
            float up = __shfl_up(x, ofs, 64);
            if (tid >= ofs) x += up;
        }
        cc[tid] = x;
        float l = __expf(x);
        lam_s[tid] = l;
        float tot = __shfl(x, 63, 64);
        ex64[tid] = __expf(tot - x);
        bet[tid] = bb[(size_t)(t0 + tid) * 32 + vh];
        lamg[(size_t)bid * 64 + tid] = l;
        if (tid == 0) l64g[bid] = __expf(tot);
    }
    __syncthreads();

    // phase A: A = K K^T (waves 0,1) -> Tb/Td ; P = Q K^T (waves 2,3) -> Pt
    {
        const unsigned short* src = (wv >= 2) ? qb : kb;
        f32x4 acc[2][4];
#pragma unroll
        for (int tm = 0; tm < 2; tm++)
#pragma unroll
            for (int tn = 0; tn < 4; tn++)
#pragma unroll
                for (int r = 0; r < 4; r++) acc[tm][tn][r] = 0.f;
#pragma unroll
        for (int ks = 0; ks < 4; ks++) {
            bf16x8 af[2], bfr[4];
#pragma unroll
            for (int tm = 0; tm < 2; tm++) {
                int row = rowb + tm * 16 + rc;
                af[tm] = *(const bf16x8*)(src + ((size_t)(t0 + row) * 16 + hk) * 128 + ks * 32 + qd * 8);
            }
#pragma unroll
            for (int tn = 0; tn < 4; tn++)
                bfr[tn] = *(const bf16x8*)(kb + ((size_t)(t0 + tn * 16 + rc) * 16 + hk) * 128 + ks * 32 + qd * 8);
#pragma unroll
            for (int tm = 0; tm < 2; tm++)
#pragma unroll
                for (int tn = 0; tn < 4; tn++)
                    acc[tm][tn] = __builtin_amdgcn_mfma_f32_16x16x32_bf16(af[tm], bfr[tn], acc[tm][tn], 0, 0, 0);
        }
        if (wv < 2) {
#pragma unroll
            for (int tm = 0; tm < 2; tm++)
#pragma unroll
                for (int tn = 0; tn < 4; tn++)
#pragma unroll
                    for (int r = 0; r < 4; r++) {
                        int i = rowb + tm * 16 + qd * 4 + r;
                        int j = tn * 16 + rc;
                        float val = acc[tm][tn][r];
                        float tv = 0.f;
                        if (i > j) tv = bet[i] * __expf(cc[i] - cc[j]) * val;
                        Tb[i * 72 + j] = f2bf(-tv);
                        if ((i >> 4) == (j >> 4) && i > j)
                            Td[(i >> 4) * 272 + (i & 15) * 17 + (j & 15)] = tv;
                    }
        } else {
#pragma unroll
            for (int tm = 0; tm < 2; tm++)
#pragma unroll
                for (int tn = 0; tn < 4; tn++)
#pragma unroll
                    for (int r = 0; r < 4; r++) {
                        int i = rowb + tm * 16 + qd * 4 + r;
                        int j = tn * 16 + rc;
                        float ev = (i >= j) ? __expf(cc[i] - cc[j]) : 0.f;
                        Pt[pbase + i * 64 + j] = f2bf(ev * acc[tm][tn][r]);
                    }
        }
    }
    // KtT: Etil-folded K^T [dk][tok]
    {
        int dk = tid >> 1, half = tid & 1;
#pragma unroll
        for (int j = 0; j < 4; j++) {
            unsigned short tmp[8];
#pragma unroll
            for (int e = 0; e < 8; e++) {
                int tok = half * 32 + j * 8 + e;
                tmp[e] = f2bf(bf2f(kb[((size_t)(t0 + tok) * 16 + hk) * 128 + dk]) * ex64[tok]);
            }
            *(uint4*)(KtT + obase + dk * 64 + half * 32 + j * 8) = *(const uint4*)tmp;
        }
    }
    __syncthreads();   // Tb/Td ready for all waves

    // per-wave forward substitution: wave wv owns col-batch cb = wv (64 cols)
    {
        int cb = wv;
        unsigned short* Xb = Xw[wv];
        float* RHS = RHSw[wv];
        for (int z = lane; z < 64 * 72 / 2; z += 64) ((unsigned int*)Xb)[z] = 0u;
#pragma unroll
        for (int B = 0; B < 4; B++) {
            f32x4 tacc[4];
#pragma unroll
            for (int cf = 0; cf < 4; cf++)
#pragma unroll
                for (int r = 0; r < 4; r++) {
                    int i = B * 16 + qd * 4 + r;
                    int c = cf * 16 + rc;
                    float v;
                    if (cb < 2)
                        v = bet[i] * vv[((size_t)(t0 + i) * 32 + vh) * 128 + cb * 64 + c];
                    else
                        v = bet[i] * lam_s[i] * bf2f(kb[((size_t)(t0 + i) * 16 + hk) * 128 + (cb - 2) * 64 + c]);
                    tacc[cf][r] = v;
                }
            __builtin_amdgcn_s_waitcnt(0xc07f);  // prior Xb writes (same wave) visible
            const int nks = (B + 1) >> 1;  // 0,1,1,2
#pragma unroll
            for (int ks = 0; ks < 2; ks++) {
                if (ks >= nks) break;
                bf16x8 af = *(const bf16x8*)&Tb[(B * 16 + rc) * 72 + ks * 32 + qd * 8];
#pragma unroll
                for (int cf = 0; cf < 4; cf++) {
                    bf16x8 bf_ = *(const bf16x8*)&Xb[(cf * 16 + rc) * 72 + ks * 32 + qd * 8];
                    tacc[cf] = __builtin_amdgcn_mfma_f32_16x16x32_bf16(af, bf_, tacc[cf], 0, 0, 0);
                }
            }
#pragma unroll
            for (int cf = 0; cf < 4; cf++)
#pragma unroll
                for (int r = 0; r < 4; r++)
                    RHS[(qd * 4 + r) * 68 + cf * 16 + rc] = tacc[cf][r];
            __builtin_amdgcn_s_waitcnt(0xc07f);  // RHS visible for transposed read
            {
                float d[16];
#pragma unroll
                for (int i2 = 0; i2 < 16; i2++) d[i2] = RHS[i2 * 68 + lane];
#pragma unroll
                for (int i2 = 1; i2 < 16; i2++)
#pragma unroll
                    for (int j2 = 0; j2 < i2; j2++)
                        d[i2] -= Td[B * 272 + i2 * 17 + j2] * d[j2];
#pragma unroll
                for (int i2 = 0; i2 < 16; i2++)
                    Xb[lane * 72 + B * 16 + i2] = f2bf(d[i2]);
            }
        }
        __builtin_amdgcn_s_waitcnt(0xc07f);
        if (cb < 2) {  // Dloc^T rows [dv = cb*64+lane][tok]
#pragma unroll
            for (int j = 0; j < 8; j++) {
                uint4 u = *(const uint4*)&Xb[lane * 72 + j * 8];
                *(uint4*)(DlT + obase + (size_t)(cb * 64 + lane) * 64 + j * 8) = u;
            }
        } else {  // W rows [tok = lane][dk]: transpose from Xb
#pragma unroll
            for (int dq = 0; dq < 8; dq++) {
                unsigned short tmp[8];
#pragma unroll
                for (int e = 0; e < 8; e++)
                    tmp[e] = Xb[(dq * 8 + e) * 72 + lane];
                *(uint4*)(Wg + obase + (size_t)lane * 128 + (cb - 2) * 64 + dq * 8) = *(const uint4*)tmp;
            }
        }
    }
}

// ---------------- serial inter-chunk scan (lean) ----------------
__global__ __launch_bounds__(256, 2) void recb_kernel(
    const unsigned short* __restrict__ qb, const float* __restrict__ lamg,
    const float* __restrict__ l64g, const unsigned short* __restrict__ Wg,
    const unsigned short* __restrict__ DlT, const unsigned short* __restrict__ KtT,
    const unsigned short* __restrict__ Pt, float* __restrict__ oo) {
    __shared__ __align__(16) unsigned short St[16 * 136];  // S^T bf16 [dv][dk]
    __shared__ __align__(16) unsigned short Dls[16 * 72];  // Dloc^T -> D'^T slice
    int bid = blockIdx.x;
    int slice = bid >> 6;           // slice-major: same head -> same XCD
    int rest = bid & 63;
    int vh = rest & 31, b = rest >> 5;
    int bh = b * 32 + vh;
    int hk = vh >> 1, dvo = slice * 16, tb = b * 1024;
    int tid = threadIdx.x, wv = tid >> 6, lane = tid & 63;
    int qd = lane >> 4, rc = lane & 15;

    f32x4 sacc[2];
#pragma unroll
    for (int tm = 0; tm < 2; tm++)
#pragma unroll
        for (int r = 0; r < 4; r++) sacc[tm][r] = 0.f;
    for (int z = tid; z < 16 * 136 / 2; z += 256) ((unsigned int*)St)[z] = 0u;
    __syncthreads();

#pragma unroll 1
    for (int ch = 0; ch < 16; ch++) {
        int bhch = bh * 16 + ch;
        size_t obase = (size_t)bhch * 8192;
        size_t pbase = (size_t)bhch * 4096;
        int t0 = tb + ch * 64;
        if (tid < 128) {
            int row = tid >> 3, t8 = (tid & 7) * 8;
            uint4 u = *(const uint4*)(DlT + obase + (dvo + row) * 64 + t8);
            *(uint4*)&Dls[row * 72 + t8] = u;
        }
        __syncthreads();
        {
            f32x4 uacc;
#pragma unroll
            for (int r = 0; r < 4; r++) uacc[r] = 0.f;
#pragma unroll
            for (int ks = 0; ks < 4; ks++) {
                bf16x8 a_ = *(const bf16x8*)&St[rc * 136 + ks * 32 + qd * 8];
                bf16x8 b_ = *(const bf16x8*)(Wg + obase + (size_t)(wv * 16 + rc) * 128 + ks * 32 + qd * 8);
                uacc = __builtin_amdgcn_mfma_f32_16x16x32_bf16(a_, b_, uacc, 0, 0, 0);
            }
#pragma unroll
            for (int r = 0; r < 4; r++) {
                int idx = (qd * 4 + r) * 72 + wv * 16 + rc;
                Dls[idx] = f2bf(bf2f(Dls[idx]) - uacc[r]);
            }
        }
        __syncthreads();
        {
            f32x4 qacc;
#pragma unroll
            for (int r = 0; r < 4; r++) qacc[r] = 0.f;
#pragma unroll
            for (int ks = 0; ks < 4; ks++) {
                bf16x8 a_ = *(const bf16x8*)(qb + ((size_t)(t0 + wv * 16 + rc) * 16 + hk) * 128 + ks * 32 + qd * 8);
                bf16x8 b_ = *(const bf16x8*)&St[rc * 136 + ks * 32 + qd * 8];
                qacc = __builtin_amdgcn_mfma_f32_16x16x32_bf16(a_, b_, qacc, 0, 0, 0);
            }
            bf16x8 bd[2];
#pragma unroll
            for (int ks = 0; ks < 2; ks++)
                bd[ks] = *(const bf16x8*)&Dls[rc * 72 + ks * 32 + qd * 8];
            f32x4 oacc;
#pragma unroll
            for (int r = 0; r < 4; r++)
                oacc[r] = lamg[(size_t)bhch * 64 + wv * 16 + qd * 4 + r] * qacc[r];
#pragma unroll
            for (int ks = 0; ks < 2; ks++) {
                bf16x8 a_ = *(const bf16x8*)(Pt + pbase + (size_t)(wv * 16 + rc) * 64 + ks * 32 + qd * 8);
                oacc = __builtin_amdgcn_mfma_f32_16x16x32_bf16(a_, bd[ks], oacc, 0, 0, 0);
            }
#pragma unroll
            for (int r = 0; r < 4; r++)
                oo[((size_t)(t0 + wv * 16 + qd * 4 + r) * 32 + vh) * 128 + dvo + rc] = oacc[r];
            float l64 = l64g[bhch];
#pragma unroll
            for (int tm = 0; tm < 2; tm++) {
#pragma unroll
                for (int r = 0; r < 4; r++) sacc[tm][r] *= l64;
#pragma unroll
                for (int ks = 0; ks < 2; ks++) {
                    bf16x8 a_ = *(const bf16x8*)(KtT + obase + (size_t)(wv * 32 + tm * 16 + rc) * 64 + ks * 32 + qd * 8);
                    sacc[tm] = __builtin_amdgcn_mfma_f32_16x16x32_bf16(a_, bd[ks], sacc[tm], 0, 0, 0);
                }
            }
        }
        __syncthreads();
#pragma unroll
        for (int tm = 0; tm < 2; tm++)
#pragma unroll
            for (int r = 0; r < 4; r++)
                St[rc * 136 + wv * 32 + tm * 16 + qd * 4 + r] = f2bf(sacc[tm][r]);
        __syncthreads();
    }
}

// ---------------- gated RMSNorm + bf16 convert ----------------
__global__ __launch_bounds__(256) void norm_kernel(
    const float* __restrict__ oo, const unsigned short* __restrict__ qkvz,
    const float* __restrict__ norm_w, unsigned short* __restrict__ yb) {
    int w = threadIdx.x >> 6, lane = threadIdx.x & 63;
    int g = blockIdx.x * 4 + w;
    int t = g >> 5, vh = g & 31;
    size_t ob = (size_t)g * 128;
    size_t zb = (size_t)t * 12288 + (size_t)(vh >> 1) * 768 + 512 + (vh & 1) * 128;
    float x0 = oo[ob + lane], x1 = oo[ob + 64 + lane];
    float z0 = bf2f(qkvz[zb + lane]), z1 = bf2f(qkvz[zb + 64 + lane]);
    float xg0 = x0 * (z0 / (1.f + expf(-z0)));
    float xg1 = x1 * (z1 / (1.f + expf(-z1)));
    float s = xg0 * xg0 + xg1 * xg1;
    s += __shfl_xor(s, 1);
    s += __shfl_xor(s, 2);
    s += __shfl_xor(s, 4);
    s += __shfl_xor(s, 8);
    s += __shfl_xor(s, 16);
    s += __shfl_xor(s, 32);
    float r = rsqrtf(s * (1.f / 128.f) + 1e-6f);
    size_t y0 = (size_t)t * 4096 + (size_t)vh * 128;
    yb[y0 + lane] = f2bf(xg0 * r * norm_w[lane]);
    yb[y0 + 64 + lane] = f2bf(xg1 * r * norm_w[64 + lane]);
}

extern "C" void kernel_launch(void* const* d_in, const int* in_sizes, int n_in,
                              void* d_out, int out_size, void* d_ws, size_t ws_size,
                              hipStream_t stream) {
    const float* hs      = (const float*)d_in[0];
    const float* w_qkvz  = (const float*)d_in[1];
    const float* w_ba    = (const float*)d_in[2];
    const float* conv_w  = (const float*)d_in[3];
    const float* dt_bias = (const float*)d_in[4];
    const float* A_log   = (const float*)d_in[5];
    const float* norm_w  = (const float*)d_in[6];
    const float* w_out   = (const float*)d_in[7];
    float* out = (float*)d_out;
    (void)in_sizes; (void)n_in; (void)out_size; (void)ws_size;

    char* p = (char*)d_ws;
    auto alloc = [&](size_t b) { char* r = p; p += (b + 255) & ~(size_t)255; return r; };
    float* gg = (float*)alloc(2048ull * 32 * 4);                         // log-decay
    float* bb = (float*)alloc(2048ull * 32 * 4);                         // beta
    unsigned short* hsb  = (unsigned short*)alloc(2048ull * 2048 * 2);   // hs bf16
    unsigned short* wqT  = (unsigned short*)alloc(12288ull * 2048 * 2);  // w_qkvz^T bf16
    unsigned short* woT  = (unsigned short*)alloc(2048ull * 4096 * 2);   // w_out^T bf16
    unsigned short* qkvz = (unsigned short*)alloc(2048ull * 12288 * 2);  // projections bf16
    unsigned short* qb16 = (unsigned short*)alloc(2048ull * 2048 * 2);   // q normed bf16
    unsigned short* kb16 = (unsigned short*)alloc(2048ull * 2048 * 2);   // k normed bf16
    float* vv = (float*)alloc(2048ull * 4096 * 4);                       // v fp32
    float* oo = (float*)alloc(2048ull * 4096 * 4);                       // recurrence out
    unsigned short* yb = (unsigned short*)alloc(2048ull * 4096 * 2);     // normed bf16
    unsigned short* Wg  = (unsigned short*)alloc(1024ull * 8192 * 2);    // W [bhch][64][128]
    unsigned short* DlT = (unsigned short*)alloc(1024ull * 8192 * 2);    // Dloc^T [bhch][128][64]
    unsigned short* KtT = (unsigned short*)alloc(1024ull * 8192 * 2);    // Ktil^T [bhch][128][64]
    unsigned short* Pt  = (unsigned short*)alloc(1024ull * 4096 * 2);    // Ptil [bhch][64][64]
    float* lamg = (float*)alloc(1024ull * 64 * 4);                       // lambda per token
    float* l64g = (float*)alloc(1024ull * 4);                            // chunk decay
    // gemm2 split-K partials reuse wqT's 50 MB (dead after gemm1); need 33.6 MB
    float* gpart = (float*)wqT;

    preproc_kernel<<<NB_CVT + NB_TQ + NB_TO + NB_BAG, 256, 0, stream>>>(
        hs, hsb, w_qkvz, wqT, w_out, woT, w_ba, A_log, dt_bias, gg, bb);
    gemm_bt_kernel<1><<<dim3(96, 16, 1), 256, 0, stream>>>(hsb, wqT, qkvz, 2048, 12288, 2048);
    conv_kernel<<<2048, 256, 0, stream>>>(qkvz, conv_w, qb16, kb16, vv);
    prep_kernel<<<1024, 256, 0, stream>>>(qb16, kb16, vv, gg, bb, Wg, DlT, KtT, Pt, lamg, l64g);
    recb_kernel<<<512, 256, 0, stream>>>(qb16, lamg, l64g, Wg, DlT, KtT, Pt, oo);
    norm_kernel<<<16384, 256, 0, stream>>>(oo, qkvz, norm_w, yb);
    gemm_bt_kernel<0><<<dim3(16, 16, 2), 256, 0, stream>>>(yb, woT, gpart, 2048, 2048, 4096);
    add_out_kernel<<<4096, 256, 0, stream>>>(gpart, out, 2048 * 2048 / 4);
}